// Round 17
// baseline (533.596 us; speedup 1.0000x reference)
//
#include <hip/hip_runtime.h>
#include <hip/hip_bf16.h>
#include <stdint.h>

namespace {

constexpr int kB = 2;
constexpr int kS = 2048;
constexpr int kD = 2048;
constexpr int kH = 16;
constexpr int kKV = 4;
constexpr int kHd = 128;
constexpr int kM = kB * kS;      // 4096 token rows
constexpr int kQKN = kD + kKV * kHd; // 2560 (q cols 0..2047, k cols 2048..2559)

using bf = __bf16;
typedef bf bf16x8 __attribute__((ext_vector_type(8)));
typedef float f32x4 __attribute__((ext_vector_type(4)));
typedef float f32x16 __attribute__((ext_vector_type(16)));

__device__ __forceinline__ f32x4 mfma16(bf16x8 a, bf16x8 b, f32x4 c) {
  return __builtin_amdgcn_mfma_f32_16x16x32_bf16(a, b, c, 0, 0, 0);
}
__device__ __forceinline__ f32x16 mfma32(bf16x8 a, bf16x8 b, f32x16 c) {
  return __builtin_amdgcn_mfma_f32_32x32x16_bf16(a, b, c, 0, 0, 0);
}

__device__ __forceinline__ void gload_lds16(const bf* g, bf* l) {
  __builtin_amdgcn_global_load_lds(
      (const __attribute__((address_space(1))) void*)(uintptr_t)g,
      (__attribute__((address_space(3))) void*)l, 16, 0, 0);
}

// ---------------- fused fp32 -> bf16 convert (all 5 inputs, one launch) ------
// float4-unit segments: x 0..2097152, Wq ..3145728, Wk ..3407872,
// Wv ..3670016, Wp ..4718592. grid = 18432 x 256 (exact: 4,718,592 units).
__global__ __launch_bounds__(256) void cvt_all(
    const float* __restrict__ x, const float* __restrict__ wq,
    const float* __restrict__ wk, const float* __restrict__ wv,
    const float* __restrict__ wp, bf* __restrict__ xb,
    bf* __restrict__ wqkvb, bf* __restrict__ wpb) {
  int i = blockIdx.x * 256 + threadIdx.x;
  const float* src; bf* dst; int off;
  if (i < 2097152)      { src = x;  dst = xb;    off = i; }
  else if (i < 3145728) { src = wq; dst = wqkvb; off = i - 2097152; }
  else if (i < 3407872) { src = wk; dst = wqkvb + (size_t)kD * kD;               off = i - 3145728; }
  else if (i < 3670016) { src = wv; dst = wqkvb + (size_t)kD * kD + 512 * kD;    off = i - 3407872; }
  else                  { src = wp; dst = wpb;   off = i - 3670016; }
  float4 v = reinterpret_cast<const float4*>(src)[off];
  union { bf h[4]; uint2 u; } o;
  o.h[0] = (bf)v.x; o.h[1] = (bf)v.y; o.h[2] = (bf)v.z; o.h[3] = (bf)v.w;
  reinterpret_cast<uint2*>(dst)[off] = o.u;
}

// ---------------- C = A * B^T body (A[M][K], B[N][K], K-contig bf16) ---------
// m97 structure. TM = tile M-rows (128 or 64). bx/by pre-swizzled by caller.
// NR=true (qkv path only): fused RMSNorm + RoPE + q_gain epilogue. Requires
// As to be the base of a CONTIGUOUS 32 KB region (SH[2][128*64]) and ssb.
template <typename CT, int TM, bool NR = false>
__device__ __forceinline__ void gemm_body(const bf* __restrict__ A, int lda,
                                          const bf* __restrict__ Bm, int ldb,
                                          CT* __restrict__ C, int ldc, int K,
                                          int bx, int by, bf* As, bf* Bs,
                                          float* ssb, const float* qgain) {
  const int tid = threadIdx.x;
  const int w = tid >> 6, lane = tid & 63;
  const int r16 = lane & 15, kg = lane >> 4;
  const int bm = by * TM, bn = bx * 128;
  const int wy = (w >> 1) * (TM / 2), wx = (w & 1) * 64;
  constexpr int MF = TM / 32;              // m-fragments per wave
  f32x4 acc[MF][4] = {};
  for (int kt = 0; kt < K; kt += 64) {
    __syncthreads();
#pragma unroll
    for (int r = 0; r < MF; r++) {         // A: TM*8 16B-units
      int u = r * 256 + tid;
      int row = u >> 3;
      int cb = ((u & 7) * 16) ^ ((row & 7) << 4);  // pre-swizzle the SOURCE
      gload_lds16(A + (size_t)(bm + row) * lda + kt + (cb >> 1),
                  As + (size_t)(r * 256 + w * 64) * 8);
    }
#pragma unroll
    for (int r = 0; r < 4; r++) {          // B: 1024 16B-units
      int u = r * 256 + tid;
      int row = u >> 3;
      int cb = ((u & 7) * 16) ^ ((row & 7) << 4);
      gload_lds16(Bm + (size_t)(bn + row) * ldb + kt + (cb >> 1),
                  Bs + (size_t)(r * 256 + w * 64) * 8);
    }
    __syncthreads();
#pragma unroll
    for (int ks = 0; ks < 2; ks++) {
      bf16x8 af[MF], bfr[4];
#pragma unroll
      for (int m = 0; m < MF; m++) {
        int row = wy + m * 16 + r16;
        af[m] = *reinterpret_cast<const bf16x8*>(
            reinterpret_cast<const char*>(As) + row * 128 +
            ((ks * 64 + kg * 16) ^ ((row & 7) << 4)));
      }
#pragma unroll
      for (int n = 0; n < 4; n++) {
        int row = wx + n * 16 + r16;
        bfr[n] = *reinterpret_cast<const bf16x8*>(
            reinterpret_cast<const char*>(Bs) + row * 128 +
            ((ks * 64 + kg * 16) ^ ((row & 7) << 4)));
      }
#pragma unroll
      for (int m = 0; m < MF; m++)
#pragma unroll
        for (int n = 0; n < 4; n++)
          acc[m][n] = mfma16(af[m], bfr[n], acc[m][n]);
    }
  }

  if constexpr (!NR) {
#pragma unroll
    for (int m = 0; m < MF; m++)
#pragma unroll
      for (int n = 0; n < 4; n++)
#pragma unroll
        for (int r = 0; r < 4; r++) {
          int row = bm + wy + m * 16 + kg * 4 + r;
          int col = bn + wx + n * 16 + r16;
          C[(size_t)row * ldc + col] = (CT)acc[m][n][r];
        }
  } else {
    // ---- fused RMSNorm + RoPE + q_gain epilogue (col tile == one head) ----
    __syncthreads();                       // all waves done with As/Bs staging
    const int wxbit = (wx != 0);
    float rmsi[MF][4];
    {
      float ssv[MF][4];
#pragma unroll
      for (int m = 0; m < MF; m++)
#pragma unroll
        for (int r = 0; r < 4; r++) {
          float s2 = 0.f;
#pragma unroll
          for (int n = 0; n < 4; n++) { float v = acc[m][n][r]; s2 += v * v; }
          s2 += __shfl_xor(s2, 1);
          s2 += __shfl_xor(s2, 2);
          s2 += __shfl_xor(s2, 4);
          s2 += __shfl_xor(s2, 8);
          ssv[m][r] = s2;                  // sum over this wave's 64 cols
        }
      if (r16 == 0) {
#pragma unroll
        for (int m = 0; m < MF; m++)
#pragma unroll
          for (int r = 0; r < 4; r++)
            ssb[(wy + m * 16 + kg * 4 + r) * 2 + wxbit] = ssv[m][r];
      }
      __syncthreads();
#pragma unroll
      for (int m = 0; m < MF; m++)
#pragma unroll
        for (int r = 0; r < 4; r++) {
          int row = wy + m * 16 + kg * 4 + r;
          float tot = ssb[row * 2 + 0] + ssb[row * 2 + 1];
          rmsi[m][r] = rsqrtf(tot * (1.0f / 128.0f) + 1.1920929e-7f);
        }
    }
    // write own normalized half into SH (= As contiguous 32 KB), swizzled
#pragma unroll
    for (int m = 0; m < MF; m++)
#pragma unroll
      for (int n = 0; n < 4; n++)
#pragma unroll
        for (int r = 0; r < 4; r++) {
          int row = wy + m * 16 + kg * 4 + r;
          int col = wx + n * 16 + r16;
          int byte = (row * 256 + col * 2) ^ ((row & 7) << 4);
          *reinterpret_cast<bf*>(reinterpret_cast<char*>(As) + byte) =
              (bf)(acc[m][n][r] * rmsi[m][r]);
        }
    __syncthreads();
    const int head = bn >> 7;
    const bool isq = bn < kD;
    const float g = isq
        ? qgain[head] * (0.08838834764831845f * 1.4426950408889634f)
        : 1.0f;
#pragma unroll
    for (int m = 0; m < MF; m++)
#pragma unroll
      for (int n = 0; n < 4; n++) {
        int fi = n * 16 + r16;             // freq index 0..63
        float invf = exp2f((float)fi * -0.20762050593046013f);
#pragma unroll
        for (int r = 0; r < 4; r++) {
          int row = wy + m * 16 + kg * 4 + r;
          int srow = (bm + row) & (kS - 1);
          float sn, cs;
          sincosf((float)srow * invf, &sn, &cs);
          int pcol = (wx ^ 64) + n * 16 + r16;
          int pbyte = (row * 256 + pcol * 2) ^ ((row & 7) << 4);
          float pv = (float)*reinterpret_cast<const bf*>(
              reinterpret_cast<const char*>(As) + pbyte);
          float own = acc[m][n][r] * rmsi[m][r];
          float out = wxbit ? (own * cs - pv * sn)   // x2 half: -x1 sn + x2 cs
                            : (own * cs + pv * sn);  // x1 half:  x1 cs + x2 sn
          C[(size_t)(bm + row) * ldc + (bn + wx + n * 16 + r16)] =
              (CT)(out * g);
        }
      }
  }
}

// Fused qkv + V^T GEMMs with 2-D chunked XCD mapping + fused norm/rope
// epilogue on the qkv segment (each 128-col tile == one head).
//  qkv (|A|=16MB,|B|=10MB): 2 col-chunks x 4 row-chunks, chunk = 10x8 blocks.
//  vt  (|A|=2MB, |B|=16MB): 8 col-chunks x 1 row-chunk,  chunk = 4x8 blocks.
__global__ __launch_bounds__(256) void gemm_qkv_vt(
    const bf* __restrict__ xb, const bf* __restrict__ wqkb,
    bf* __restrict__ qkbuf, const bf* __restrict__ wvb,
    bf* __restrict__ vtbuf, const float* __restrict__ qg) {
  __shared__ bf SH[2][128 * 64];           // As|Bs contiguous (32 KB)
  __shared__ float ssb[128 * 2];
  const int bid = blockIdx.x;
  if (bid < 640) {
    int xcd = bid & 7, i = bid >> 3;        // i in 0..79
    int cx = xcd & 1, cy = xcd >> 1;        // 2 x 4 chunks
    int bx = cx * 10 + i % 10;              // 20 cols
    int by = cy * 8 + i / 10;               // 32 rows
    gemm_body<bf, 128, true>(xb, kD, wqkb, kD, qkbuf, kQKN, kD,
                             bx, by, SH[0], SH[1], ssb, qg);
  } else {
    int b2 = bid - 640;
    int xcd = b2 & 7, i = b2 >> 3;          // i in 0..31
    int bx = xcd * 4 + i % 4;               // 32 cols
    int by = i / 4;                         // 8 rows (TM=64)
    gemm_body<bf, 64>(wvb, kD, xb, kD, vtbuf, kM, kD,
                      bx, by, SH[0], SH[1], nullptr, nullptr);
  }
}

// proj: out = yb @ Wproj^T (512 blocks, grid 16x32).
// |A|=16MB, |B|=8MB: 2 col-chunks x 4 row-chunks, chunk = 8x8 blocks.
__global__ __launch_bounds__(256) void gemm_proj(const bf* __restrict__ yb,
                                                 const bf* __restrict__ wpb,
                                                 float* __restrict__ out) {
  __shared__ bf As[128 * 64];
  __shared__ bf Bs[128 * 64];
  const int bid = blockIdx.x;
  int xcd = bid & 7, i = bid >> 3;          // i in 0..63
  int cx = xcd & 1, cy = xcd >> 1;          // 2 x 4 chunks
  int bx = cx * 8 + i % 8;                  // 16 cols
  int by = cy * 8 + i / 8;                  // 32 rows
  gemm_body<float, 128>(yb, kD, wpb, kD, out, kD, kD, bx, by, As, Bs,
                        nullptr, nullptr);
}

// ---------------- causal flash attention (32x32 MFMA, P in-register) ----------
// Block = 4 waves. Wave = 32 q x 32 kv (qhalf=w&1, kvhalf=w>>1); two phases
// (j, 31-j) => exactly 33 kv rounds per block. Counted-vmcnt two-barrier round.
// Vs LDS staging is ESSENTIAL (R12: per-XCD L2 can't hold vt against K/Q
// streaming; launch_bounds(256,3) spills the accumulator).
__global__ __launch_bounds__(256, 2) void attn_kernel(const bf* __restrict__ qk,
                                                      const bf* __restrict__ vt,
                                                      bf* __restrict__ y) {
  __shared__ bf Ks[2][64 * 128];   // [kv][d], swizzled 256B rows (32 KB)
  __shared__ bf Vs[2][128 * 64];   // [d][kv], swizzled 128B rows (32 KB)
  __shared__ float Ml[2][64][2];   // kv-half=1 waves' (m, l)
  const int tid = threadIdx.x;
  const int w = tid >> 6, lane = tid & 63;
  const int q32 = lane & 31, hi = lane >> 5;
  const int qhalf = w & 1, kvhalf = w >> 1;
  const int bh = blockIdx.x;              // 0..31
  const int pairIdx = blockIdx.y;         // 0..15
  const int b = bh >> 4, h = bh & 15, kvh = h >> 2;
  const size_t rowbase = (size_t)b * kS;
  const bf* kbase = qk + kD + kvh * kHd;                       // + row*kQKN
  const bf* vbase = vt + (size_t)(kvh * kHd) * kM + b * kS;    // + d*kM + s

  // hoisted per-lane staging sources (kt-invariant part)
  const bf* gK[4]; const bf* gV[4];
#pragma unroll
  for (int r = 0; r < 4; r++) {
    int u = r * 256 + tid;
    int krow = u >> 4, c16 = u & 15;          // 16 x 16B units per 256B K row
    gK[r] = kbase + (size_t)(rowbase + krow) * kQKN +
            (((c16 * 16) ^ ((krow & 7) << 4)) >> 1);
    int vrow = u >> 3, c8 = u & 7;            // 8 x 16B units per 128B V row
    gV[r] = vbase + (size_t)vrow * kM +
            (((c8 * 16) ^ ((vrow & 7) << 4)) >> 1);
  }

  auto stage = [&](int buf, int kt) {
    const size_t ko = (size_t)kt * (size_t)(64 * kQKN);  // uniform
    const int vo = kt * 64;                              // uniform
#pragma unroll
    for (int r = 0; r < 4; r++)
      gload_lds16(gK[r] + ko, Ks[buf] + (size_t)(r * 256 + w * 64) * 8);
#pragma unroll
    for (int r = 0; r < 4; r++)
      gload_lds16(gV[r] + vo, Vs[buf] + (size_t)(r * 256 + w * 64) * 8);
  };

#pragma unroll 1
  for (int ph = 0; ph < 2; ph++) {
    const int j = ph ? (31 - pairIdx) : pairIdx;    // q-tile index 0..31
    const int q0 = j * 64;
    const int qg0 = q0 + qhalf * 32;                // wave's q base
    const int qrow = qg0 + q32;                     // lane's q row
    const int kvoff = kvhalf * 32;                  // wave's kv sub-block

    // Q fragments (B-operand: col=q32, k-dim d = dc*16 + hi*8 + jj)
    bf16x8 qf[8];
#pragma unroll
    for (int dc = 0; dc < 8; dc++)
      qf[dc] = *reinterpret_cast<const bf16x8*>(
          qk + (rowbase + qrow) * kQKN + h * kHd + dc * 16 + hi * 8);

    f32x16 o[4] = {};
    float mrun = -1e30f, lrun = 0.f;

    int cur = 0;
    stage(0, 0);

    for (int kt = 0; kt <= j; kt++) {
      // barrier A: all waves done reading buf[cur^1] (compute kt-1)
      asm volatile("s_barrier" ::: "memory");
      if (kt < j) {
        stage(cur ^ 1, kt + 1);              // issue next tile's 8 loads
        asm volatile("s_waitcnt vmcnt(8)" ::: "memory");  // tile-kt loads done
      } else {
        asm volatile("s_waitcnt vmcnt(0)" ::: "memory");  // drain at phase end
      }
      // barrier B: everyone's tile-kt loads are in LDS
      asm volatile("s_barrier" ::: "memory");

      if (kt * 64 + kvoff <= qg0 + 31) {    // wave-uniform skip
        // S^T[32kv][32q] via swapped mfma(K, Q): col=q32, row kv = crow(r,hi)
        f32x16 sf = {};
        const int krow = kvoff + q32;
        const char* ksrow = reinterpret_cast<const char*>(Ks[cur]) + krow * 256;
        const int kswz = (krow & 7) << 4;
        __builtin_amdgcn_s_setprio(1);
#pragma unroll
        for (int dc = 0; dc < 8; dc++) {
          bf16x8 kf = *reinterpret_cast<const bf16x8*>(
              ksrow + ((dc * 32 + hi * 16) ^ kswz));
          sf = mfma32(kf, qf[dc], sf);
        }
        __builtin_amdgcn_s_setprio(0);

        // causal mask (only when the 32-kv strip straddles the diagonal)
        if (kt * 64 + kvoff + 31 > qg0) {
#pragma unroll
          for (int r = 0; r < 16; r++) {
            int kgl = kt * 64 + kvoff + (r & 3) + 8 * (r >> 2) + 4 * hi;
            sf[r] = (kgl <= qrow) ? sf[r] : -1e30f;
          }
        }

        // row max (q = q32; other hi-half holds the other 16 kv's)
        float rmax = sf[0];
#pragma unroll
        for (int r = 1; r < 16; r++) rmax = fmaxf(rmax, sf[r]);
        rmax = fmaxf(rmax, __shfl_xor(rmax, 32));

        // defer-max rescale (THR=8 in log2 domain)
        if (!__all(rmax <= mrun + 8.0f)) {
          float mnew = fmaxf(mrun, rmax);
          float resc = exp2f(mrun - mnew);
          mrun = mnew;
          lrun *= resc;
          float rq[16];
#pragma unroll
          for (int r = 0; r < 16; r++)
            rq[r] = __shfl(resc, (r & 3) + 8 * (r >> 2) + 4 * hi);
#pragma unroll
          for (int db = 0; db < 4; db++)
#pragma unroll
            for (int r = 0; r < 16; r++) o[db][r] *= rq[r];
        }

        // P = exp2(S - m), row sum
        float rsum = 0.f;
#pragma unroll
        for (int r = 0; r < 16; r++) {
          float p = exp2f(sf[r] - mrun);
          sf[r] = p;
          rsum += p;
        }
        rsum += __shfl_xor(rsum, 32);
        lrun += rsum;

        // PV A-frags in-register: 8 cvt_pk + 4 permlane32_swap.
        bf16x8 pa[2];
        {
          uint32_t wa[4], wb[4];
#pragma unroll
          for (int g = 0; g < 4; g++) {
            asm("v_cvt_pk_bf16_f32 %0, %1, %2"
                : "=v"(wa[g]) : "v"(sf[4 * g + 0]), "v"(sf[4 * g + 1]));
            asm("v_cvt_pk_bf16_f32 %0, %1, %2"
                : "=v"(wb[g]) : "v"(sf[4 * g + 2]), "v"(sf[4 * g + 3]));
          }
          asm volatile("v_permlane32_swap_b32 %0, %1" : "+v"(wa[0]), "+v"(wa[1]));
          asm volatile("v_permlane32_swap_b32 %0, %1" : "+v"(wb[0]), "+v"(wb[1]));
          asm volatile("v_permlane32_swap_b32 %0, %1" : "+v"(wa[2]), "+v"(wa[3]));
          asm volatile("v_permlane32_swap_b32 %0, %1" : "+v"(wb[2]), "+v"(wb[3]));
          union { uint32_t u[4]; bf16x8 v; } p0, p1;
          p0.u[0] = wa[0]; p0.u[1] = wb[0]; p0.u[2] = wa[1]; p0.u[3] = wb[1];
          p1.u[0] = wa[2]; p1.u[1] = wb[2]; p1.u[2] = wa[3]; p1.u[3] = wb[3];
          pa[0] = p0.v; pa[1] = p1.v;
        }

        // O += P V  (B = Vs rows d: col=q32 -> d)
        __builtin_amdgcn_s_setprio(1);
#pragma unroll
        for (int c = 0; c < 2; c++)
#pragma unroll
          for (int db = 0; db < 4; db++) {
            int vrow = db * 32 + q32;
            bf16x8 vb = *reinterpret_cast<const bf16x8*>(
                reinterpret_cast<const char*>(Vs[cur]) + vrow * 128 +
                ((kvhalf * 64 + c * 32 + hi * 16) ^ ((vrow & 7) << 4)));
            o[db] = mfma32(pa[c], vb, o[db]);
          }
        __builtin_amdgcn_s_setprio(0);
      }
      cur ^= 1;
    }

    // ---- exact merge of the two kv-half partials, then store ----
    __syncthreads();                       // all PV reads of Ks/Vs done
    float* mb = reinterpret_cast<float*>(Ks);   // 32 KB = 8192 floats, reused
    if (w >= 2) {
      Ml[w - 2][lane][0] = mrun;
      Ml[w - 2][lane][1] = lrun;
      int base = (w - 2) * 4096;
#pragma unroll
      for (int db = 0; db < 4; db++)
#pragma unroll
        for (int r = 0; r < 16; r++)
          mb[base + (db * 16 + r) * 64 + lane] = o[db][r];
    }
    __syncthreads();                       // partials visible
    if (w < 2) {
      float m1 = Ml[w][lane][0], l1 = Ml[w][lane][1];
      float m = fmaxf(mrun, m1);
      float f0 = exp2f(mrun - m), f1 = exp2f(m1 - m);
      float linv = 1.0f / (lrun * f0 + l1 * f1);
      float av = f0 * linv, bv = f1 * linv;
      float aq[16], bq[16];
#pragma unroll
      for (int r = 0; r < 16; r++) {
        int cr = (r & 3) + 8 * (r >> 2) + 4 * hi;
        aq[r] = __shfl(av, cr);
        bq[r] = __shfl(bv, cr);
      }
      int base = w * 4096;
#pragma unroll
      for (int db = 0; db < 4; db++)
#pragma unroll
        for (int r = 0; r < 16; r++) {
          float pv = mb[base + (db * 16 + r) * 64 + lane];
          float res = o[db][r] * aq[r] + pv * bq[r];
          int s = qg0 + (r & 3) + 8 * (r >> 2) + 4 * hi;
          int d = db * 32 + q32;
          y[(rowbase + s) * kD + h * kHd + d] = (bf)res;
        }
    }
    __syncthreads();                       // mb reads done before next staging
  }
}

}  // namespace

extern "C" void kernel_launch(void* const* d_in, const int* in_sizes, int n_in,
                              void* d_out, int out_size, void* d_ws, size_t ws_size,
                              hipStream_t stream) {
  const float* x  = (const float*)d_in[0];
  const float* Wq = (const float*)d_in[1];
  const float* Wk = (const float*)d_in[2];
  const float* Wv = (const float*)d_in[3];
  const float* Wp = (const float*)d_in[4];
  const float* qg = (const float*)d_in[5];

  // workspace layout (bf16)
  bf* xb    = (bf*)d_ws;                       // 4096*2048
  bf* wqkvb = xb + (size_t)kM * kD;            // 3072*2048 (Wq|Wk|Wv rows)
  bf* wpb   = wqkvb + (size_t)3072 * kD;       // 2048*2048
  bf* qkbuf = wpb + (size_t)kD * kD;           // 4096*2560
  bf* vtbuf = qkbuf + (size_t)kM * kQKN;       // 512*4096 (V^T: [kv d][token])
  bf* yb    = vtbuf + (size_t)512 * kM;        // 4096*2048

  // one fused convert launch (18432 x 256 = 4,718,592 float4 units, exact)
  cvt_all<<<18432, 256, 0, stream>>>(x, Wq, Wk, Wv, Wp, xb, wqkvb, wpb);

  // fused: qk = normrope(x @ [Wq;Wk]^T) (blocks 0..639, fused epilogue)
  //        + vt = Wv @ x^T (blocks 640..895)
  gemm_qkv_vt<<<896, 256, 0, stream>>>(
      xb, wqkvb, qkbuf, wqkvb + (size_t)(kD + 512) * kD, vtbuf, qg);

  // flash attention -> yb
  attn_kernel<<<dim3(kB * kH, 16), 256, 0, stream>>>(qkbuf, vtbuf, yb);

  // out = yb @ Wproj^T  (M=4096, N=2048, K=2048) -> fp32 d_out, 512 blocks
  gemm_proj<<<512, 256, 0, stream>>>(yb, wpb, (float*)d_out);
}

// Round 18
// 216.421 us; speedup vs baseline: 2.4655x; 2.4655x over previous
//
#include <hip/hip_runtime.h>
#include <hip/hip_bf16.h>
#include <stdint.h>

namespace {

constexpr int kB = 2;
constexpr int kS = 2048;
constexpr int kD = 2048;
constexpr int kH = 16;
constexpr int kKV = 4;
constexpr int kHd = 128;
constexpr int kM = kB * kS;      // 4096 token rows
constexpr int kQKN = kD + kKV * kHd; // 2560 (q cols 0..2047, k cols 2048..2559)

using bf = __bf16;
typedef bf bf16x8 __attribute__((ext_vector_type(8)));
typedef float f32x4 __attribute__((ext_vector_type(4)));
typedef float f32x16 __attribute__((ext_vector_type(16)));

__device__ __forceinline__ f32x4 mfma16(bf16x8 a, bf16x8 b, f32x4 c) {
  return __builtin_amdgcn_mfma_f32_16x16x32_bf16(a, b, c, 0, 0, 0);
}
__device__ __forceinline__ f32x16 mfma32(bf16x8 a, bf16x8 b, f32x16 c) {
  return __builtin_amdgcn_mfma_f32_32x32x16_bf16(a, b, c, 0, 0, 0);
}

__device__ __forceinline__ void gload_lds16(const bf* g, bf* l) {
  __builtin_amdgcn_global_load_lds(
      (const __attribute__((address_space(1))) void*)(uintptr_t)g,
      (__attribute__((address_space(3))) void*)l, 16, 0, 0);
}

// ---------------- fused fp32 -> bf16 convert (all 5 inputs, one launch) ------
// float4-unit segments: x 0..2097152, Wq ..3145728, Wk ..3407872,
// Wv ..3670016, Wp ..4718592. grid = 18432 x 256 (exact: 4,718,592 units).
__global__ __launch_bounds__(256) void cvt_all(
    const float* __restrict__ x, const float* __restrict__ wq,
    const float* __restrict__ wk, const float* __restrict__ wv,
    const float* __restrict__ wp, bf* __restrict__ xb,
    bf* __restrict__ wqkvb, bf* __restrict__ wpb) {
  int i = blockIdx.x * 256 + threadIdx.x;
  const float* src; bf* dst; int off;
  if (i < 2097152)      { src = x;  dst = xb;    off = i; }
  else if (i < 3145728) { src = wq; dst = wqkvb; off = i - 2097152; }
  else if (i < 3407872) { src = wk; dst = wqkvb + (size_t)kD * kD;               off = i - 3145728; }
  else if (i < 3670016) { src = wv; dst = wqkvb + (size_t)kD * kD + 512 * kD;    off = i - 3407872; }
  else                  { src = wp; dst = wpb;   off = i - 3670016; }
  float4 v = reinterpret_cast<const float4*>(src)[off];
  union { bf h[4]; uint2 u; } o;
  o.h[0] = (bf)v.x; o.h[1] = (bf)v.y; o.h[2] = (bf)v.z; o.h[3] = (bf)v.w;
  reinterpret_cast<uint2*>(dst)[off] = o.u;
}

// ---------------- C = A * B^T body (A[M][K], B[N][K], K-contig bf16) ---------
// m97 structure. TM = tile M-rows (128 or 64). bx/by pre-swizzled by caller.
// NOTE (R16 lesson): do NOT add epilogues that keep acc live through
// register-hungry phases — the allocator spills acc to scratch (1.2 GB).
template <typename CT, int TM>
__device__ __forceinline__ void gemm_body(const bf* __restrict__ A, int lda,
                                          const bf* __restrict__ Bm, int ldb,
                                          CT* __restrict__ C, int ldc, int K,
                                          int bx, int by, bf* As, bf* Bs) {
  const int tid = threadIdx.x;
  const int w = tid >> 6, lane = tid & 63;
  const int r16 = lane & 15, kg = lane >> 4;
  const int bm = by * TM, bn = bx * 128;
  const int wy = (w >> 1) * (TM / 2), wx = (w & 1) * 64;
  constexpr int MF = TM / 32;              // m-fragments per wave
  f32x4 acc[MF][4] = {};
  for (int kt = 0; kt < K; kt += 64) {
    __syncthreads();
#pragma unroll
    for (int r = 0; r < MF; r++) {         // A: TM*8 16B-units
      int u = r * 256 + tid;
      int row = u >> 3;
      int cb = ((u & 7) * 16) ^ ((row & 7) << 4);  // pre-swizzle the SOURCE
      gload_lds16(A + (size_t)(bm + row) * lda + kt + (cb >> 1),
                  As + (size_t)(r * 256 + w * 64) * 8);
    }
#pragma unroll
    for (int r = 0; r < 4; r++) {          // B: 1024 16B-units
      int u = r * 256 + tid;
      int row = u >> 3;
      int cb = ((u & 7) * 16) ^ ((row & 7) << 4);
      gload_lds16(Bm + (size_t)(bn + row) * ldb + kt + (cb >> 1),
                  Bs + (size_t)(r * 256 + w * 64) * 8);
    }
    __syncthreads();
#pragma unroll
    for (int ks = 0; ks < 2; ks++) {
      bf16x8 af[MF], bfr[4];
#pragma unroll
      for (int m = 0; m < MF; m++) {
        int row = wy + m * 16 + r16;
        af[m] = *reinterpret_cast<const bf16x8*>(
            reinterpret_cast<const char*>(As) + row * 128 +
            ((ks * 64 + kg * 16) ^ ((row & 7) << 4)));
      }
#pragma unroll
      for (int n = 0; n < 4; n++) {
        int row = wx + n * 16 + r16;
        bfr[n] = *reinterpret_cast<const bf16x8*>(
            reinterpret_cast<const char*>(Bs) + row * 128 +
            ((ks * 64 + kg * 16) ^ ((row & 7) << 4)));
      }
#pragma unroll
      for (int m = 0; m < MF; m++)
#pragma unroll
        for (int n = 0; n < 4; n++)
          acc[m][n] = mfma16(af[m], bfr[n], acc[m][n]);
    }
  }
#pragma unroll
  for (int m = 0; m < MF; m++)
#pragma unroll
    for (int n = 0; n < 4; n++)
#pragma unroll
      for (int r = 0; r < 4; r++) {
        int row = bm + wy + m * 16 + kg * 4 + r;
        int col = bn + wx + n * 16 + r16;
        C[(size_t)row * ldc + col] = (CT)acc[m][n][r];
      }
}

// Fused qkv + V^T GEMMs with 2-D chunked XCD mapping (fetch model:
// fetch = c_col*|A| + c_row*|B|, c_col*c_row = 8 XCD chunks):
//  qkv (|A|=16MB,|B|=10MB): 2 col-chunks x 4 row-chunks, chunk = 10x8 blocks.
//  vt  (|A|=2MB, |B|=16MB): 8 col-chunks x 1 row-chunk,  chunk = 4x8 blocks.
// Per-chunk K-slice working set ~300KB << 4MB per-XCD L2.
__global__ __launch_bounds__(256) void gemm_qkv_vt(
    const bf* __restrict__ xb, const bf* __restrict__ wqkb,
    bf* __restrict__ qkbuf, const bf* __restrict__ wvb,
    bf* __restrict__ vtbuf) {
  __shared__ bf As[128 * 64];
  __shared__ bf Bs[128 * 64];
  const int bid = blockIdx.x;
  if (bid < 640) {
    int xcd = bid & 7, i = bid >> 3;        // i in 0..79
    int cx = xcd & 1, cy = xcd >> 1;        // 2 x 4 chunks
    int bx = cx * 10 + i % 10;              // 20 cols
    int by = cy * 8 + i / 10;               // 32 rows
    gemm_body<bf, 128>(xb, kD, wqkb, kD, qkbuf, kQKN, kD, bx, by, As, Bs);
  } else {
    int b2 = bid - 640;
    int xcd = b2 & 7, i = b2 >> 3;          // i in 0..31
    int bx = xcd * 4 + i % 4;               // 32 cols
    int by = i / 4;                         // 8 rows (TM=64)
    gemm_body<bf, 64>(wvb, kD, xb, kD, vtbuf, kM, kD, bx, by, As, Bs);
  }
}

// proj: out = yb @ Wproj^T (512 blocks, grid 16x32).
// |A|=16MB, |B|=8MB: 2 col-chunks x 4 row-chunks, chunk = 8x8 blocks.
__global__ __launch_bounds__(256) void gemm_proj(const bf* __restrict__ yb,
                                                 const bf* __restrict__ wpb,
                                                 float* __restrict__ out) {
  __shared__ bf As[128 * 64];
  __shared__ bf Bs[128 * 64];
  const int bid = blockIdx.x;
  int xcd = bid & 7, i = bid >> 3;          // i in 0..63
  int cx = xcd & 1, cy = xcd >> 1;          // 2 x 4 chunks
  int bx = cx * 8 + i % 8;                  // 16 cols
  int by = cy * 8 + i / 8;                  // 32 rows
  gemm_body<float, 128>(yb, kD, wpb, kD, out, kD, kD, bx, by, As, Bs);
}

// ---------------- RMSNorm + RoPE + gain, in place on qk buffer ----------------
__global__ __launch_bounds__(256) void normrope(bf* __restrict__ qk,
                                                const float* __restrict__ qgain) {
  const int tid = threadIdx.x;
  const int w = tid >> 6, lane = tid & 63;
  int v = blockIdx.x * 4 + w;             // 0 .. B*S*(H+KV)-1
  int b = v / (kS * (kH + kKV));
  int rem = v % (kS * (kH + kKV));
  int s = rem / (kH + kKV);
  int j = rem % (kH + kKV);               // 0..15 q heads, 16..19 kv heads
  int colbase = (j < kH) ? j * kHd : kD + (j - kH) * kHd;
  size_t base = (size_t)(b * kS + s) * kQKN + colbase;
  float e1 = (float)qk[base + lane];
  float e2 = (float)qk[base + 64 + lane];
  float ss = e1 * e1 + e2 * e2;
#pragma unroll
  for (int m = 1; m < 64; m <<= 1) ss += __shfl_xor(ss, m);
  float inv = rsqrtf(ss * (1.0f / 128.0f) + 1.1920929e-7f);
  e1 *= inv; e2 *= inv;
  // 10000^(-lane/64) == exp2(-lane * log2(10000)/64)
  float invfreq = exp2f((float)lane * -0.20762050593046013f);
  float ang = (float)s * invfreq;
  float sn, cs;
  sincosf(ang, &sn, &cs);
  float o1 = e1 * cs + e2 * sn;
  float o2 = -e1 * sn + e2 * cs;
  if (j < kH) {
    // fold q_gain * (1/sqrt(128)) * log2(e)  -> exp2-domain softmax
    float g = qgain[j] * (0.08838834764831845f * 1.4426950408889634f);
    o1 *= g; o2 *= g;
  }
  qk[base + lane] = (bf)o1;
  qk[base + 64 + lane] = (bf)o2;
}

// ---------------- causal flash attention (32x32 MFMA, P in-register) ----------
// Block = 4 waves. Wave = 32 q x 32 kv (qhalf=w&1, kvhalf=w>>1); two phases
// (j, 31-j) => exactly 33 kv rounds per block. Counted-vmcnt two-barrier round.
// Vs LDS staging is ESSENTIAL (R12: per-XCD L2 can't hold vt against K/Q
// streaming; launch_bounds(256,3) spills the accumulator).
__global__ __launch_bounds__(256, 2) void attn_kernel(const bf* __restrict__ qk,
                                                      const bf* __restrict__ vt,
                                                      bf* __restrict__ y) {
  __shared__ bf Ks[2][64 * 128];   // [kv][d], swizzled 256B rows (32 KB)
  __shared__ bf Vs[2][128 * 64];   // [d][kv], swizzled 128B rows (32 KB)
  __shared__ float Ml[2][64][2];   // kv-half=1 waves' (m, l)
  const int tid = threadIdx.x;
  const int w = tid >> 6, lane = tid & 63;
  const int q32 = lane & 31, hi = lane >> 5;
  const int qhalf = w & 1, kvhalf = w >> 1;
  const int bh = blockIdx.x;              // 0..31
  const int pairIdx = blockIdx.y;         // 0..15
  const int b = bh >> 4, h = bh & 15, kvh = h >> 2;
  const size_t rowbase = (size_t)b * kS;
  const bf* kbase = qk + kD + kvh * kHd;                       // + row*kQKN
  const bf* vbase = vt + (size_t)(kvh * kHd) * kM + b * kS;    // + d*kM + s

  // hoisted per-lane staging sources (kt-invariant part)
  const bf* gK[4]; const bf* gV[4];
#pragma unroll
  for (int r = 0; r < 4; r++) {
    int u = r * 256 + tid;
    int krow = u >> 4, c16 = u & 15;          // 16 x 16B units per 256B K row
    gK[r] = kbase + (size_t)(rowbase + krow) * kQKN +
            (((c16 * 16) ^ ((krow & 7) << 4)) >> 1);
    int vrow = u >> 3, c8 = u & 7;            // 8 x 16B units per 128B V row
    gV[r] = vbase + (size_t)vrow * kM +
            (((c8 * 16) ^ ((vrow & 7) << 4)) >> 1);
  }

  auto stage = [&](int buf, int kt) {
    const size_t ko = (size_t)kt * (size_t)(64 * kQKN);  // uniform
    const int vo = kt * 64;                              // uniform
#pragma unroll
    for (int r = 0; r < 4; r++)
      gload_lds16(gK[r] + ko, Ks[buf] + (size_t)(r * 256 + w * 64) * 8);
#pragma unroll
    for (int r = 0; r < 4; r++)
      gload_lds16(gV[r] + vo, Vs[buf] + (size_t)(r * 256 + w * 64) * 8);
  };

#pragma unroll 1
  for (int ph = 0; ph < 2; ph++) {
    const int j = ph ? (31 - pairIdx) : pairIdx;    // q-tile index 0..31
    const int q0 = j * 64;
    const int qg0 = q0 + qhalf * 32;                // wave's q base
    const int qrow = qg0 + q32;                     // lane's q row
    const int kvoff = kvhalf * 32;                  // wave's kv sub-block

    // Q fragments (B-operand: col=q32, k-dim d = dc*16 + hi*8 + jj)
    bf16x8 qf[8];
#pragma unroll
    for (int dc = 0; dc < 8; dc++)
      qf[dc] = *reinterpret_cast<const bf16x8*>(
          qk + (rowbase + qrow) * kQKN + h * kHd + dc * 16 + hi * 8);

    f32x16 o[4] = {};
    float mrun = -1e30f, lrun = 0.f;

    int cur = 0;
    stage(0, 0);

    for (int kt = 0; kt <= j; kt++) {
      // barrier A: all waves done reading buf[cur^1] (compute kt-1)
      asm volatile("s_barrier" ::: "memory");
      if (kt < j) {
        stage(cur ^ 1, kt + 1);              // issue next tile's 8 loads
        asm volatile("s_waitcnt vmcnt(8)" ::: "memory");  // tile-kt loads done
      } else {
        asm volatile("s_waitcnt vmcnt(0)" ::: "memory");  // drain at phase end
      }
      // barrier B: everyone's tile-kt loads are in LDS
      asm volatile("s_barrier" ::: "memory");

      if (kt * 64 + kvoff <= qg0 + 31) {    // wave-uniform skip
        // S^T[32kv][32q] via swapped mfma(K, Q): col=q32, row kv = crow(r,hi)
        f32x16 sf = {};
        const int krow = kvoff + q32;
        const char* ksrow = reinterpret_cast<const char*>(Ks[cur]) + krow * 256;
        const int kswz = (krow & 7) << 4;
        __builtin_amdgcn_s_setprio(1);
#pragma unroll
        for (int dc = 0; dc < 8; dc++) {
          bf16x8 kf = *reinterpret_cast<const bf16x8*>(
              ksrow + ((dc * 32 + hi * 16) ^ kswz));
          sf = mfma32(kf, qf[dc], sf);
        }
        __builtin_amdgcn_s_setprio(0);

        // causal mask (only when the 32-kv strip straddles the diagonal)
        if (kt * 64 + kvoff + 31 > qg0) {
#pragma unroll
          for (int r = 0; r < 16; r++) {
            int kgl = kt * 64 + kvoff + (r & 3) + 8 * (r >> 2) + 4 * hi;
            sf[r] = (kgl <= qrow) ? sf[r] : -1e30f;
          }
        }

        // row max (q = q32; other hi-half holds the other 16 kv's)
        float rmax = sf[0];
#pragma unroll
        for (int r = 1; r < 16; r++) rmax = fmaxf(rmax, sf[r]);
        rmax = fmaxf(rmax, __shfl_xor(rmax, 32));

        // defer-max rescale (THR=8 in log2 domain)
        if (!__all(rmax <= mrun + 8.0f)) {
          float mnew = fmaxf(mrun, rmax);
          float resc = exp2f(mrun - mnew);
          mrun = mnew;
          lrun *= resc;
          float rq[16];
#pragma unroll
          for (int r = 0; r < 16; r++)
            rq[r] = __shfl(resc, (r & 3) + 8 * (r >> 2) + 4 * hi);
#pragma unroll
          for (int db = 0; db < 4; db++)
#pragma unroll
            for (int r = 0; r < 16; r++) o[db][r] *= rq[r];
        }

        // P = exp2(S - m), row sum
        float rsum = 0.f;
#pragma unroll
        for (int r = 0; r < 16; r++) {
          float p = exp2f(sf[r] - mrun);
          sf[r] = p;
          rsum += p;
        }
        rsum += __shfl_xor(rsum, 32);
        lrun += rsum;

        // PV A-frags in-register: 8 cvt_pk + 4 permlane32_swap.
        bf16x8 pa[2];
        {
          uint32_t wa[4], wb[4];
#pragma unroll
          for (int g = 0; g < 4; g++) {
            asm("v_cvt_pk_bf16_f32 %0, %1, %2"
                : "=v"(wa[g]) : "v"(sf[4 * g + 0]), "v"(sf[4 * g + 1]));
            asm("v_cvt_pk_bf16_f32 %0, %1, %2"
                : "=v"(wb[g]) : "v"(sf[4 * g + 2]), "v"(sf[4 * g + 3]));
          }
          asm volatile("v_permlane32_swap_b32 %0, %1" : "+v"(wa[0]), "+v"(wa[1]));
          asm volatile("v_permlane32_swap_b32 %0, %1" : "+v"(wb[0]), "+v"(wb[1]));
          asm volatile("v_permlane32_swap_b32 %0, %1" : "+v"(wa[2]), "+v"(wa[3]));
          asm volatile("v_permlane32_swap_b32 %0, %1" : "+v"(wb[2]), "+v"(wb[3]));
          union { uint32_t u[4]; bf16x8 v; } p0, p1;
          p0.u[0] = wa[0]; p0.u[1] = wb[0]; p0.u[2] = wa[1]; p0.u[3] = wb[1];
          p1.u[0] = wa[2]; p1.u[1] = wb[2]; p1.u[2] = wa[3]; p1.u[3] = wb[3];
          pa[0] = p0.v; pa[1] = p1.v;
        }

        // O += P V  (B = Vs rows d: col=q32 -> d)
        __builtin_amdgcn_s_setprio(1);
#pragma unroll
        for (int c = 0; c < 2; c++)
#pragma unroll
          for (int db = 0; db < 4; db++) {
            int vrow = db * 32 + q32;
            bf16x8 vb = *reinterpret_cast<const bf16x8*>(
                reinterpret_cast<const char*>(Vs[cur]) + vrow * 128 +
                ((kvhalf * 64 + c * 32 + hi * 16) ^ ((vrow & 7) << 4)));
            o[db] = mfma32(pa[c], vb, o[db]);
          }
        __builtin_amdgcn_s_setprio(0);
      }
      cur ^= 1;
    }

    // ---- exact merge of the two kv-half partials, then store ----
    __syncthreads();                       // all PV reads of Ks/Vs done
    float* mb = reinterpret_cast<float*>(Ks);   // 32 KB = 8192 floats, reused
    if (w >= 2) {
      Ml[w - 2][lane][0] = mrun;
      Ml[w - 2][lane][1] = lrun;
      int base = (w - 2) * 4096;
#pragma unroll
      for (int db = 0; db < 4; db++)
#pragma unroll
        for (int r = 0; r < 16; r++)
          mb[base + (db * 16 + r) * 64 + lane] = o[db][r];
    }
    __syncthreads();                       // partials visible
    if (w < 2) {
      float m1 = Ml[w][lane][0], l1 = Ml[w][lane][1];
      float m = fmaxf(mrun, m1);
      float f0 = exp2f(mrun - m), f1 = exp2f(m1 - m);
      float linv = 1.0f / (lrun * f0 + l1 * f1);
      float av = f0 * linv, bv = f1 * linv;
      float aq[16], bq[16];
#pragma unroll
      for (int r = 0; r < 16; r++) {
        int cr = (r & 3) + 8 * (r >> 2) + 4 * hi;
        aq[r] = __shfl(av, cr);
        bq[r] = __shfl(bv, cr);
      }
      int base = w * 4096;
#pragma unroll
      for (int db = 0; db < 4; db++)
#pragma unroll
        for (int r = 0; r < 16; r++) {
          float pv = mb[base + (db * 16 + r) * 64 + lane];
          float res = o[db][r] * aq[r] + pv * bq[r];
          int s = qg0 + (r & 3) + 8 * (r >> 2) + 4 * hi;
          int d = db * 32 + q32;
          y[(rowbase + s) * kD + h * kHd + d] = (bf)res;
        }
    }
    __syncthreads();                       // mb reads done before next staging
  }
}

}  // namespace

extern "C" void kernel_launch(void* const* d_in, const int* in_sizes, int n_in,
                              void* d_out, int out_size, void* d_ws, size_t ws_size,
                              hipStream_t stream) {
  const float* x  = (const float*)d_in[0];
  const float* Wq = (const float*)d_in[1];
  const float* Wk = (const float*)d_in[2];
  const float* Wv = (const float*)d_in[3];
  const float* Wp = (const float*)d_in[4];
  const float* qg = (const float*)d_in[5];

  // workspace layout (bf16)
  bf* xb    = (bf*)d_ws;                       // 4096*2048
  bf* wqkvb = xb + (size_t)kM * kD;            // 3072*2048 (Wq|Wk|Wv rows)
  bf* wpb   = wqkvb + (size_t)3072 * kD;       // 2048*2048
  bf* qkbuf = wpb + (size_t)kD * kD;           // 4096*2560
  bf* vtbuf = qkbuf + (size_t)kM * kQKN;       // 512*4096 (V^T: [kv d][token])
  bf* yb    = vtbuf + (size_t)512 * kM;        // 4096*2048

  // one fused convert launch (18432 x 256 = 4,718,592 float4 units, exact)
  cvt_all<<<18432, 256, 0, stream>>>(x, Wq, Wk, Wv, Wp, xb, wqkvb, wpb);

  // fused: qk = x @ [Wq;Wk]^T (blocks 0..639) + vt = Wv @ x^T (blocks 640..895)
  gemm_qkv_vt<<<896, 256, 0, stream>>>(
      xb, wqkvb, qkbuf, wqkvb + (size_t)(kD + 512) * kD, vtbuf);

  // RMSNorm + RoPE + gain (q also pre-scaled for exp2-domain softmax)
  normrope<<<(kB * kS * (kH + kKV)) / 4, 256, 0, stream>>>(qkbuf, qg);

  // flash attention -> yb
  attn_kernel<<<dim3(kB * kH, 16), 256, 0, stream>>>(qkbuf, vtbuf, yb);

  // out = yb @ Wproj^T  (M=4096, N=2048, K=2048) -> fp32 d_out, 512 blocks
  gemm_proj<<<512, 256, 0, stream>>>(yb, wpb, (float*)d_out);
}